// Round 7
// baseline (136.326 us; speedup 1.0000x reference)
//
#include <hip/hip_runtime.h>
#include <math.h>

// YOLOv1 loss: S=7, B=2, C=1, BATCH=32768
// predictions: (BATCH, 7, 7, 11) fp32   targets: (BATCH, 7, 7, 6) fp32
// out: 5 fp32 scalars: total, coord/bs, conf_obj/bs, conf_noobj/bs, class/bs
//
// Stage-1: 1024-thread blocks, 1024 cells/block (LDS 69.6 KB -> 2 blocks/CU
// = 32 waves/CU, full occupancy), perfectly-coalesced float4 staging,
// fast-math intrinsics. 1568 blocks (4x fewer, longer-lived than R6) to cut
// block-churn / barrier-drain overhead. One float4 partial per block -> d_ws.
// Stage-2: one 1024-thread block reduces 1568 partials, writes 5 outputs.

#define PRED_C 11
#define TGT_C  6
#define CPB    1024           // cells per block == threads per block
#define LAMBDA_COORD 5.0f
#define LAMBDA_NOOBJ 0.5f
#define EPSV 1e-6f

// fast sigmoid: |rel err| ~1e-6, far inside the 1.98 absmax budget
__device__ __forceinline__ float fsig(float x) {
    return __builtin_amdgcn_rcpf(1.0f + __expf(-x));
}

__global__ __launch_bounds__(CPB) void yolo_partial_kernel(
    const float* __restrict__ pred,
    const float* __restrict__ tgt,
    float* __restrict__ partials)   // gridDim.x float4s
{
    __shared__ float sp[CPB * PRED_C];   // 45056 B
    __shared__ float st[CPB * TGT_C];    // 24576 B
    __shared__ float red[16][4];

    const int tid = threadIdx.x;
    const long long blockCell = (long long)blockIdx.x * CPB;

    // ---- stage: fully-coalesced float4 loads into LDS (lane-contiguous) ----
    {
        const float4* gp = (const float4*)(pred + blockCell * PRED_C);
        float4* lp = (float4*)sp;
        lp[tid]        = gp[tid];
        lp[tid + 1024] = gp[tid + 1024];
        if (tid < CPB * PRED_C / 4 - 2048) lp[tid + 2048] = gp[tid + 2048];
        const float4* gt = (const float4*)(tgt + blockCell * TGT_C);
        float4* lt = (float4*)st;
        lt[tid] = gt[tid];
        if (tid < CPB * TGT_C / 4 - 1024) lt[tid + 1024] = gt[tid + 1024];
    }
    __syncthreads();

    // ---- per-cell loss (stride-11 LDS reads: free 2-way aliasing) ----
    const float* p = sp + tid * PRED_C;
    const float* t = st + tid * TGT_C;

    const float tx = t[0], ty = t[1], tw = t[2], th = t[3];
    const float tconf = t[4], tcls = t[5];
    const float obj   = (tconf == 1.0f) ? 1.0f : 0.0f;
    const float noobj = (tconf == 0.0f) ? 1.0f : 0.0f;

    const float t1x = tx - tw * 0.5f, t1y = ty - th * 0.5f;
    const float t2x = tx + tw * 0.5f, t2y = ty + th * 0.5f;
    const float tarea = tw * th;

    float iou[2], sx[2], sy[2], aw[2], ah[2], scf[2];
    #pragma unroll
    for (int b = 0; b < 2; ++b) {
        sx[b]  = fsig(p[b * 5 + 0]);
        sy[b]  = fsig(p[b * 5 + 1]);
        scf[b] = fsig(p[b * 5 + 4]);
        aw[b]  = fabsf(p[b * 5 + 2]);
        ah[b]  = fabsf(p[b * 5 + 3]);
        const float p1x = sx[b] - aw[b] * 0.5f, p1y = sy[b] - ah[b] * 0.5f;
        const float p2x = sx[b] + aw[b] * 0.5f, p2y = sy[b] + ah[b] * 0.5f;
        const float ix = fminf(p2x, t2x) - fmaxf(p1x, t1x);
        const float iy = fminf(p2y, t2y) - fmaxf(p1y, t1y);
        const float inter = fmaxf(ix, 0.0f) * fmaxf(iy, 0.0f);
        const float parea = aw[b] * ah[b];
        iou[b] = inter * __builtin_amdgcn_rcpf(parea + tarea - inter + EPSV);
    }
    // jnp.argmax: first occurrence of max -> box1 only if strictly greater
    const int best = (iou[1] > iou[0]) ? 1 : 0;

    const float dx = sx[best] - tx;
    const float dy = sy[best] - ty;
    const float dw = __builtin_amdgcn_sqrtf(aw[best] + EPSV) -
                     __builtin_amdgcn_sqrtf(tw + EPSV);
    const float dh = __builtin_amdgcn_sqrtf(ah[best] + EPSV) -
                     __builtin_amdgcn_sqrtf(th + EPSV);
    float coord = LAMBDA_COORD * obj * ((dx * dx + dy * dy) + (dw * dw + dh * dh));

    const float sc = scf[best];
    float conf_obj = obj * (sc - tconf) * (sc - tconf);

    const float d0 = scf[0] - tconf;
    const float d1 = scf[1] - tconf;
    float conf_noobj = LAMBDA_NOOBJ * noobj * (d0 * d0 + d1 * d1);

    const float pc = p[10];
    const float bce = fmaxf(pc, 0.0f) - pc * tcls +
                      __logf(1.0f + __expf(-fabsf(pc)));
    float class_loss = obj * bce;

    // ---- reduction: wave shuffle (64-wide) -> cross-wave LDS -> float4 store
    #pragma unroll
    for (int off = 32; off >= 1; off >>= 1) {
        coord      += __shfl_down(coord, off);
        conf_obj   += __shfl_down(conf_obj, off);
        conf_noobj += __shfl_down(conf_noobj, off);
        class_loss += __shfl_down(class_loss, off);
    }
    const int wave = tid >> 6;
    const int lane = tid & 63;
    __syncthreads();   // staging reads done before red[] reuse of LDS
    if (lane == 0) {
        red[wave][0] = coord;
        red[wave][1] = conf_obj;
        red[wave][2] = conf_noobj;
        red[wave][3] = class_loss;
    }
    __syncthreads();
    if (tid == 0) {
        float4 v = make_float4(0.f, 0.f, 0.f, 0.f);
        #pragma unroll
        for (int w = 0; w < 16; ++w) {
            v.x += red[w][0];
            v.y += red[w][1];
            v.z += red[w][2];
            v.w += red[w][3];
        }
        ((float4*)partials)[blockIdx.x] = v;
    }
}

__global__ __launch_bounds__(1024) void yolo_final_kernel(
    const float* __restrict__ partials,
    float* __restrict__ out,
    int nblk,
    float inv_bs)
{
    __shared__ float red[16][4];
    const int tid = threadIdx.x;

    float c = 0.f, co = 0.f, cn = 0.f, cl = 0.f;
    for (int i = tid; i < nblk; i += 1024) {
        const float4 v = ((const float4*)partials)[i];
        c += v.x; co += v.y; cn += v.z; cl += v.w;
    }
    #pragma unroll
    for (int off = 32; off >= 1; off >>= 1) {
        c  += __shfl_down(c, off);
        co += __shfl_down(co, off);
        cn += __shfl_down(cn, off);
        cl += __shfl_down(cl, off);
    }
    const int wave = tid >> 6;
    const int lane = tid & 63;
    if (lane == 0) {
        red[wave][0] = c;
        red[wave][1] = co;
        red[wave][2] = cn;
        red[wave][3] = cl;
    }
    __syncthreads();
    if (tid == 0) {
        float sc = 0.f, sco = 0.f, scn = 0.f, scl = 0.f;
        #pragma unroll
        for (int w = 0; w < 16; ++w) {
            sc  += red[w][0];
            sco += red[w][1];
            scn += red[w][2];
            scl += red[w][3];
        }
        out[0] = (sc + sco + scn + scl) * inv_bs;
        out[1] = sc  * inv_bs;
        out[2] = sco * inv_bs;
        out[3] = scn * inv_bs;
        out[4] = scl * inv_bs;
    }
}

extern "C" void kernel_launch(void* const* d_in, const int* in_sizes, int n_in,
                              void* d_out, int out_size, void* d_ws, size_t ws_size,
                              hipStream_t stream) {
    const float* pred = (const float*)d_in[0];
    const float* tgt  = (const float*)d_in[1];
    float* out = (float*)d_out;
    float* partials = (float*)d_ws;

    const long long batch = (long long)in_sizes[0] / (7 * 7 * PRED_C);
    const long long cells = batch * 49;         // 1,605,632
    const int nblk = (int)(cells / CPB);        // 1568 exact

    yolo_partial_kernel<<<nblk, CPB, 0, stream>>>(pred, tgt, partials);
    yolo_final_kernel<<<1, 1024, 0, stream>>>(partials, out, nblk,
                                              1.0f / (float)batch);
}

// Round 8
// 131.060 us; speedup vs baseline: 1.0402x; 1.0402x over previous
//
#include <hip/hip_runtime.h>
#include <math.h>

// YOLOv1 loss: S=7, B=2, C=1, BATCH=32768
// predictions: (BATCH, 7, 7, 11) fp32   targets: (BATCH, 7, 7, 6) fp32
// out: 5 fp32 scalars: total, coord/bs, conf_obj/bs, conf_noobj/bs, class/bs
//
// R8: double-buffered async pipeline. 1568 blocks x 256 threads, 4 tiles each
// (6272 = 1568*4). Tile staging uses __builtin_amdgcn_global_load_lds width=16
// (wave-uniform LDS base + lane*16 — layout matches exactly). Prefetch of tile
// k+1 overlaps compute of tile k; __syncthreads' vmcnt(0) drain lands AFTER
// compute, so the memory pipe stays ~100% duty cycle (fix for the measured
// latency-bound regime: VALUBusy 12%, occupancy 40%, 2 TB/s in R5).

#define PRED_C 11
#define TGT_C  6
#define TPB    256            // threads per block == cells per tile
#define TILES_PER_BLOCK 4
#define LAMBDA_COORD 5.0f
#define LAMBDA_NOOBJ 0.5f
#define EPSV 1e-6f

typedef unsigned int u32;

// async 16B/lane global->LDS DMA; lds dest = wave-uniform base + lane*16
__device__ __forceinline__ void gll16(const float* g, float* l) {
    __builtin_amdgcn_global_load_lds(
        (const __attribute__((address_space(1))) u32*)g,
        (__attribute__((address_space(3))) u32*)l,
        16, 0, 0);
}

// fast sigmoid: |rel err| ~1e-6, far inside the 1.98 absmax budget
__device__ __forceinline__ float fsig(float x) {
    return __builtin_amdgcn_rcpf(1.0f + __expf(-x));
}

__global__ __launch_bounds__(TPB) void yolo_partial_kernel(
    const float* __restrict__ pred,
    const float* __restrict__ tgt,
    float* __restrict__ partials,   // gridDim.x float4s
    int ntiles)
{
    // double-buffered tile staging: pred 2816 floats, tgt 1536 floats per tile
    __shared__ __align__(16) float sp[2][TPB * PRED_C];  // 2 x 11264 B
    __shared__ __align__(16) float st[2][TPB * TGT_C];   // 2 x  6144 B
    __shared__ float red[4][4];

    const int tid = threadIdx.x;
    const int wv  = tid >> 6;
    const int ln  = tid & 63;

    // stage tile t into buffer b: 17 chunks of 1024 B, round-robin over 4 waves
    auto stage = [&](int t, int b) {
        const float* pbase = pred + (long long)t * (TPB * PRED_C);
        const float* tbase = tgt  + (long long)t * (TPB * TGT_C);
        #pragma unroll
        for (int o = wv; o < 17; o += 4) {
            if (o < 11) gll16(pbase + o * 256 + ln * 4, &sp[b][o * 256]);
            else        gll16(tbase + (o - 11) * 256 + ln * 4, &st[b][(o - 11) * 256]);
        }
    };

    float acc_coord = 0.f, acc_cobj = 0.f, acc_cnoobj = 0.f, acc_cls = 0.f;

    int tile = blockIdx.x;
    stage(tile, 0);
    __syncthreads();              // vmcnt(0) drain + barrier: buf0 ready

    int cur = 0;
    #pragma unroll
    for (int i = 0; i < TILES_PER_BLOCK; ++i) {
        // prefetch next tile into the other buffer (in flight during compute)
        const int tn = tile + gridDim.x;
        if (i < TILES_PER_BLOCK - 1 && tn < ntiles) stage(tn, cur ^ 1);

        // ---- compute current tile (1 cell/thread from LDS) ----
        const float* p = &sp[cur][tid * PRED_C];
        const float* t = &st[cur][tid * TGT_C];

        const float tx = t[0], ty = t[1], tw = t[2], th = t[3];
        const float tconf = t[4], tcls = t[5];
        const float obj   = (tconf == 1.0f) ? 1.0f : 0.0f;
        const float noobj = (tconf == 0.0f) ? 1.0f : 0.0f;

        const float t1x = tx - tw * 0.5f, t1y = ty - th * 0.5f;
        const float t2x = tx + tw * 0.5f, t2y = ty + th * 0.5f;
        const float tarea = tw * th;

        float iou[2], sx[2], sy[2], aw[2], ah[2], scf[2];
        #pragma unroll
        for (int b = 0; b < 2; ++b) {
            sx[b]  = fsig(p[b * 5 + 0]);
            sy[b]  = fsig(p[b * 5 + 1]);
            scf[b] = fsig(p[b * 5 + 4]);
            aw[b]  = fabsf(p[b * 5 + 2]);
            ah[b]  = fabsf(p[b * 5 + 3]);
            const float p1x = sx[b] - aw[b] * 0.5f, p1y = sy[b] - ah[b] * 0.5f;
            const float p2x = sx[b] + aw[b] * 0.5f, p2y = sy[b] + ah[b] * 0.5f;
            const float ix = fminf(p2x, t2x) - fmaxf(p1x, t1x);
            const float iy = fminf(p2y, t2y) - fmaxf(p1y, t1y);
            const float inter = fmaxf(ix, 0.0f) * fmaxf(iy, 0.0f);
            const float parea = aw[b] * ah[b];
            iou[b] = inter * __builtin_amdgcn_rcpf(parea + tarea - inter + EPSV);
        }
        // jnp.argmax: first occurrence of max -> box1 only if strictly greater
        const int best = (iou[1] > iou[0]) ? 1 : 0;

        const float dx = sx[best] - tx;
        const float dy = sy[best] - ty;
        const float dw = __builtin_amdgcn_sqrtf(aw[best] + EPSV) -
                         __builtin_amdgcn_sqrtf(tw + EPSV);
        const float dh = __builtin_amdgcn_sqrtf(ah[best] + EPSV) -
                         __builtin_amdgcn_sqrtf(th + EPSV);
        acc_coord += LAMBDA_COORD * obj * ((dx * dx + dy * dy) + (dw * dw + dh * dh));

        const float sc = scf[best];
        acc_cobj += obj * (sc - tconf) * (sc - tconf);

        const float d0 = scf[0] - tconf;
        const float d1 = scf[1] - tconf;
        acc_cnoobj += LAMBDA_NOOBJ * noobj * (d0 * d0 + d1 * d1);

        const float pc = p[10];
        const float bce = fmaxf(pc, 0.0f) - pc * tcls +
                          __logf(1.0f + __expf(-fabsf(pc)));
        acc_cls += obj * bce;

        // drain prefetch DMA (overlapped with the compute above) + WAR barrier
        __syncthreads();
        cur ^= 1;
        tile = tn;
    }

    // ---- block reduction: wave shuffle (64-wide) -> cross-wave LDS ----
    #pragma unroll
    for (int off = 32; off >= 1; off >>= 1) {
        acc_coord  += __shfl_down(acc_coord, off);
        acc_cobj   += __shfl_down(acc_cobj, off);
        acc_cnoobj += __shfl_down(acc_cnoobj, off);
        acc_cls    += __shfl_down(acc_cls, off);
    }
    if (ln == 0) {
        red[wv][0] = acc_coord;
        red[wv][1] = acc_cobj;
        red[wv][2] = acc_cnoobj;
        red[wv][3] = acc_cls;
    }
    __syncthreads();
    if (tid == 0) {
        float4 v;
        v.x = red[0][0] + red[1][0] + red[2][0] + red[3][0];
        v.y = red[0][1] + red[1][1] + red[2][1] + red[3][1];
        v.z = red[0][2] + red[1][2] + red[2][2] + red[3][2];
        v.w = red[0][3] + red[1][3] + red[2][3] + red[3][3];
        ((float4*)partials)[blockIdx.x] = v;
    }
}

__global__ __launch_bounds__(1024) void yolo_final_kernel(
    const float* __restrict__ partials,
    float* __restrict__ out,
    int nblk,
    float inv_bs)
{
    __shared__ float red[16][4];
    const int tid = threadIdx.x;

    float c = 0.f, co = 0.f, cn = 0.f, cl = 0.f;
    for (int i = tid; i < nblk; i += 1024) {
        const float4 v = ((const float4*)partials)[i];
        c += v.x; co += v.y; cn += v.z; cl += v.w;
    }
    #pragma unroll
    for (int off = 32; off >= 1; off >>= 1) {
        c  += __shfl_down(c, off);
        co += __shfl_down(co, off);
        cn += __shfl_down(cn, off);
        cl += __shfl_down(cl, off);
    }
    const int wave = tid >> 6;
    const int lane = tid & 63;
    if (lane == 0) {
        red[wave][0] = c;
        red[wave][1] = co;
        red[wave][2] = cn;
        red[wave][3] = cl;
    }
    __syncthreads();
    if (tid == 0) {
        float sc = 0.f, sco = 0.f, scn = 0.f, scl = 0.f;
        #pragma unroll
        for (int w = 0; w < 16; ++w) {
            sc  += red[w][0];
            sco += red[w][1];
            scn += red[w][2];
            scl += red[w][3];
        }
        out[0] = (sc + sco + scn + scl) * inv_bs;
        out[1] = sc  * inv_bs;
        out[2] = sco * inv_bs;
        out[3] = scn * inv_bs;
        out[4] = scl * inv_bs;
    }
}

extern "C" void kernel_launch(void* const* d_in, const int* in_sizes, int n_in,
                              void* d_out, int out_size, void* d_ws, size_t ws_size,
                              hipStream_t stream) {
    const float* pred = (const float*)d_in[0];
    const float* tgt  = (const float*)d_in[1];
    float* out = (float*)d_out;
    float* partials = (float*)d_ws;

    const long long batch = (long long)in_sizes[0] / (7 * 7 * PRED_C);
    const long long cells = batch * 49;              // 1,605,632
    const int ntiles = (int)(cells / TPB);           // 6272 exact
    const int nblk = ntiles / TILES_PER_BLOCK;       // 1568 exact

    yolo_partial_kernel<<<nblk, TPB, 0, stream>>>(pred, tgt, partials, ntiles);
    yolo_final_kernel<<<1, 1024, 0, stream>>>(partials, out, nblk,
                                              1.0f / (float)batch);
}